// Round 4
// baseline (946.481 us; speedup 1.0000x reference)
//
#include <hip/hip_runtime.h>
#include <hip/hip_bf16.h>

#define T_TOK 4096
#define DDIM  2048
#define FDIM  4096
#define NEXP  8
#define MAXROWS 9216   // T*2 + 8*128 padding (128-grain segments)
#define MAXMT   72     // MAXROWS/128 (gemm2 m-tiles)
#define NT256   40     // max 256-grain m-tiles: sum ceil(seg/256) <= 40

typedef __attribute__((ext_vector_type(4))) float f32x4;
typedef __attribute__((ext_vector_type(8))) short bf16x8;

__device__ __forceinline__ unsigned short f2b(float f) {
  union { float f; unsigned u; } c; c.f = f;
  unsigned r = c.u + 0x7FFFu + ((c.u >> 16) & 1u);
  return (unsigned short)(r >> 16);
}

// async global->LDS, 16B per lane; LDS dest must be wave-uniform base (+lane*16 implicit)
__device__ __forceinline__ void gload_lds16(const void* g, void* l) {
  __builtin_amdgcn_global_load_lds((__attribute__((address_space(1))) void*)(g),
                                   (__attribute__((address_space(3))) void*)(l),
                                   16, 0, 0);
}

// ---------------- gating: one wave per token ----------------
__global__ void gate_topk(const float* __restrict__ x, const float* __restrict__ gw,
                          int* __restrict__ sel_e, float* __restrict__ sel_w) {
  const int t = blockIdx.x * 4 + (threadIdx.x >> 6);
  const int l = threadIdx.x & 63;
  const float* xr = x + (size_t)t * DDIM;
  float acc[8];
  #pragma unroll
  for (int e = 0; e < 8; ++e) acc[e] = 0.f;
  for (int d = l; d < DDIM; d += 64) {
    const float xv = xr[d];
    const float* g = gw + d * 8;
    #pragma unroll
    for (int e = 0; e < 8; ++e) acc[e] = fmaf(xv, g[e], acc[e]);
  }
  #pragma unroll
  for (int e = 0; e < 8; ++e) {
    float v = acc[e];
    #pragma unroll
    for (int off = 32; off; off >>= 1) v += __shfl_xor(v, off, 64);
    acc[e] = v;
  }
  if (l == 0) {
    int e0 = 0; float v0 = acc[0];
    #pragma unroll
    for (int e = 1; e < 8; ++e) if (acc[e] > v0) { v0 = acc[e]; e0 = e; }
    int e1 = -1; float v1 = -1e30f;
    #pragma unroll
    for (int e = 0; e < 8; ++e) if (e != e0 && acc[e] > v1) { v1 = acc[e]; e1 = e; }
    const float ex = __expf(v1 - v0);
    const float w0 = 1.f / (1.f + ex);
    sel_e[t * 2] = e0; sel_e[t * 2 + 1] = e1;
    sel_w[t * 2] = w0; sel_w[t * 2 + 1] = ex * w0;
  }
}

// ---------------- per-expert lists (single block) ----------------
__global__ void build_lists(const int* __restrict__ sel_e, const float* __restrict__ sel_w,
                            int* __restrict__ cnt, int* __restrict__ base,
                            int* __restrict__ row_token, float* __restrict__ row_gw,
                            int* __restrict__ tE, int* __restrict__ tM0,
                            int* __restrict__ tEnd) {
  __shared__ int c[8], f[8], b[9];
  const int tid = threadIdx.x;
  if (tid < 8) { c[tid] = 0; f[tid] = 0; }
  __syncthreads();
  for (int t = tid; t < T_TOK; t += 256) {
    atomicAdd(&c[sel_e[t * 2]], 1);
    atomicAdd(&c[sel_e[t * 2 + 1]], 1);
  }
  __syncthreads();
  if (tid == 0) {
    int r = 0;
    for (int e = 0; e < 8; ++e) { b[e] = r; r += ((c[e] + 127) >> 7) << 7; }
    b[8] = r;
    for (int e = 0; e < 8; ++e) { cnt[e] = c[e]; base[e] = b[e]; }
    base[8] = r;
    // 256-grain tile table for gemm1
    int nt = 0;
    for (int e = 0; e < 8; ++e)
      for (int i = b[e]; i < b[e + 1]; i += 256) {
        tE[nt] = e; tM0[nt] = i; tEnd[nt] = b[e + 1]; ++nt;
      }
    for (; nt < NT256; ++nt) { tE[nt] = 0; tM0[nt] = -1; tEnd[nt] = 0; }
  }
  __syncthreads();
  for (int i = tid; i < MAXROWS; i += 256) { row_token[i] = -1; row_gw[i] = 0.f; }
  __syncthreads();
  for (int t = tid; t < T_TOK; t += 256) {
    #pragma unroll
    for (int k = 0; k < 2; ++k) {
      const int e = sel_e[t * 2 + k];
      const int p = b[e] + atomicAdd(&f[e], 1);
      row_token[p] = t; row_gw[p] = sel_w[t * 2 + k];
    }
  }
}

// ---------------- gather x rows -> compact bf16 ----------------
__global__ void gather_x(const float* __restrict__ x, const int* __restrict__ base,
                         const int* __restrict__ row_token, unsigned short* __restrict__ xc) {
  const int i = blockIdx.x;
  if (i >= base[8]) return;
  const int t = row_token[i];
  const int tid = threadIdx.x;
  union { uint4 u; unsigned short s[8]; } o;
  if (t < 0) { o.u.x = 0u; o.u.y = 0u; o.u.z = 0u; o.u.w = 0u; }
  else {
    const float4* src = (const float4*)(x + (size_t)t * DDIM + tid * 8);
    const float4 a = src[0], bb = src[1];
    o.s[0] = f2b(a.x);  o.s[1] = f2b(a.y);  o.s[2] = f2b(a.z);  o.s[3] = f2b(a.w);
    o.s[4] = f2b(bb.x); o.s[5] = f2b(bb.y); o.s[6] = f2b(bb.z); o.s[7] = f2b(bb.w);
  }
  ((uint4*)(xc + (size_t)i * DDIM))[tid] = o.u;
}

// ---------------- transpose + fp32->bf16 convert ----------------
__global__ void conv_t(const float* __restrict__ src, unsigned short* __restrict__ dst,
                       int R, int C, int rowMul, int rowAdd) {
  const int e = blockIdx.z;
  const int r0 = blockIdx.x * 64, c0 = blockIdx.y * 64;
  const float* s = src + (size_t)e * R * C + (size_t)r0 * C + c0;
  unsigned short* d = dst + (size_t)e * R * C * rowMul;
  __shared__ unsigned short T[64][68];
  const int t = threadIdx.x;
  {
    const int i = t >> 2, jb = (t & 3) * 16;
    #pragma unroll
    for (int k2 = 0; k2 < 4; ++k2) {
      const float4 v = *(const float4*)(s + (size_t)i * C + jb + k2 * 4);
      uint2 uu;
      uu.x = (unsigned)f2b(v.x) | ((unsigned)f2b(v.y) << 16);
      uu.y = (unsigned)f2b(v.z) | ((unsigned)f2b(v.w) << 16);
      *(uint2*)&T[i][jb + k2 * 4] = uu;
    }
  }
  __syncthreads();
  {
    const int j = t >> 2, ib = (t & 3) * 16;
    union { uint4 q[2]; unsigned short s16[16]; } pk;
    #pragma unroll
    for (int i = 0; i < 16; ++i) pk.s16[i] = T[ib + i][j];
    unsigned short* drow = d + (size_t)(rowMul * (c0 + j) + rowAdd) * R + r0 + ib;
    *(uint4*)drow = pk.q[0];
    *(uint4*)(drow + 8) = pk.q[1];
  }
}

// ---------------- GEMM1: 256x256 tile, BK=64, 8 waves, 4-phase counted-vmcnt ----------
// hidden = silu(xc@w1[e]) * (xc@w3[e]); B = w13t[e][8192][2048] (even rows w1, odd w3)
// Staging units per K-tile (order matters for the vmcnt(4) guarantee chain):
//   u0 = A rows {0-63,128-191}  (mf-half0 of both wm windows)
//   u1 = B rows {0-31,64-95,128-159,192-223}  (nf-half0 of all wn)
//   u2 = B rows +32 (nf-half1)
//   u3 = A rows {64-127,192-255} (mf-half1)
// Phase p of group t stages unit p of tile t+1; vmcnt(4) before every phase barrier
// guarantees unit staged at phase X is in LDS by end of phase X+2 (~1200cy slack),
// matching reads: u0,u1 @ p1; u2 @ p2; u3 @ p3. Never drains to 0 in the loop (T4).
__global__ __launch_bounds__(512, 2)
void moe_gemm1(const unsigned short* __restrict__ A,
               const unsigned short* __restrict__ B,
               const int* __restrict__ tE, const int* __restrict__ tM0,
               const int* __restrict__ tEnd,
               unsigned short* __restrict__ hid) {
  __shared__ __align__(16) unsigned short As[2][16384];  // [buf][256 rows][64 k]
  __shared__ __align__(16) unsigned short Bs[2][16384];

  const int nwg = gridDim.x;             // 1280 (= 8*160)
  const int q8 = nwg >> 3;
  const int bid = blockIdx.x;
  const int swz = (bid & 7) * q8 + (bid >> 3);
  const int mt = swz % NT256;            // m-fast: consecutive swz share B-panel
  const int nt = swz / NT256;
  const int m0 = tM0[mt];
  if (m0 < 0) return;
  const int e = tE[mt];
  const int mend = tEnd[mt];
  const int n0 = nt * 256;

  const unsigned short* Bp = B + (size_t)e * (8192ull * 2048ull);

  const int tid = threadIdx.x;
  const int w = tid >> 6;
  const int l = tid & 63;
  const int wm = w >> 2, wn = w & 3;     // 2 x 4 waves, wave tile 128x64
  const int lr = l & 15, kc = l >> 4;

  const int rowT = tid >> 3;             // 0..63
  const int csE = ((tid & 7) ^ (rowT & 7)) << 3;  // swizzled chunk src offset (elems)

  f32x4 acc[8][4];
  #pragma unroll
  for (int i = 0; i < 8; ++i)
    #pragma unroll
    for (int j = 0; j < 4; ++j) acc[i][j] = (f32x4){0.f, 0.f, 0.f, 0.f};

  // ---- staging helpers (2 x gload_lds16 each; dest wave-uniform base) ----
  auto stageA = [&](int buf, int h, int kk) {
    #pragma unroll
    for (int q = 0; q < 2; ++q) {
      int gr = m0 + h * 64 + q * 128 + rowT;
      gr = gr > MAXROWS - 1 ? MAXROWS - 1 : gr;
      gload_lds16(A + (size_t)gr * DDIM + kk + csE,
                  &As[buf][(h * 64 + q * 128 + w * 8) * 64]);
    }
  };
  auto stageB = [&](int buf, int h, int kk) {
    #pragma unroll
    for (int q = 0; q < 2; ++q) {
      const int row = h * 32 + (q * 2 + (rowT >> 5)) * 64 + (rowT & 31);
      const int rbase = h * 32 + (q * 2 + (w >> 2)) * 64 + (w & 3) * 8;
      gload_lds16(Bp + (size_t)(n0 + row) * DDIM + kk + csE,
                  &Bs[buf][rbase * 64]);
    }
  };

  // ---- prologue: full tile 0, drain, publish ----
  stageA(0, 0, 0);
  stageB(0, 0, 0);
  stageB(0, 1, 0);
  stageA(0, 1, 0);
  asm volatile("s_waitcnt vmcnt(0)" ::: "memory");
  asm volatile("s_barrier" ::: "memory");

  #define QUAD(MB, NB)                                                          \
    __builtin_amdgcn_s_setprio(1);                                              \
    _Pragma("unroll")                                                           \
    for (int mf = 0; mf < 4; ++mf)                                              \
      _Pragma("unroll")                                                         \
      for (int nf = 0; nf < 2; ++nf)                                            \
        _Pragma("unroll")                                                       \
        for (int ks = 0; ks < 2; ++ks)                                          \
          acc[(MB) + mf][(NB) + nf] = __builtin_amdgcn_mfma_f32_16x16x32_bf16(  \
              a[mf][ks], b[(NB) + nf][ks], acc[(MB) + mf][(NB) + nf], 0, 0, 0); \
    __builtin_amdgcn_s_setprio(0);

  for (int t = 0; t < DDIM / 64; ++t) {
    const int cur = t & 1, nxt = cur ^ 1;
    const int kk = (t + 1) * 64;
    const bool more = t < DDIM / 64 - 1;
    const unsigned short* Ac = As[cur];
    const unsigned short* Bc = Bs[cur];
    bf16x8 a[4][2], b[4][2];

    // ---- phase 1: read A mf0-3 + B nf0-1; stage u0(t+1); q(0..3, 0..1) ----
    #pragma unroll
    for (int mf = 0; mf < 4; ++mf) {
      const int r = wm * 128 + mf * 16 + lr;
      #pragma unroll
      for (int ks = 0; ks < 2; ++ks)
        a[mf][ks] = *(const bf16x8*)(Ac + r * 64 + (((ks * 4 + kc) ^ (r & 7)) << 3));
    }
    #pragma unroll
    for (int nf = 0; nf < 2; ++nf) {
      const int r = wn * 64 + nf * 16 + lr;
      #pragma unroll
      for (int ks = 0; ks < 2; ++ks)
        b[nf][ks] = *(const bf16x8*)(Bc + r * 64 + (((ks * 4 + kc) ^ (r & 7)) << 3));
    }
    if (more) {
      stageA(nxt, 0, kk);
      asm volatile("s_waitcnt vmcnt(4)" ::: "memory");
    } else {
      asm volatile("s_waitcnt vmcnt(0)" ::: "memory");
    }
    asm volatile("s_barrier" ::: "memory");
    QUAD(0, 0)
    asm volatile("s_barrier" ::: "memory");

    // ---- phase 2: read B nf2-3; stage u1(t+1); q(0..3, 2..3) ----
    #pragma unroll
    for (int nf = 2; nf < 4; ++nf) {
      const int r = wn * 64 + nf * 16 + lr;
      #pragma unroll
      for (int ks = 0; ks < 2; ++ks)
        b[nf][ks] = *(const bf16x8*)(Bc + r * 64 + (((ks * 4 + kc) ^ (r & 7)) << 3));
    }
    if (more) {
      stageB(nxt, 0, kk);
      asm volatile("s_waitcnt vmcnt(4)" ::: "memory");
    }
    asm volatile("s_barrier" ::: "memory");
    QUAD(0, 2)
    asm volatile("s_barrier" ::: "memory");

    // ---- phase 3: read A mf4-7; stage u2(t+1); q(4..7, 0..1) ----
    #pragma unroll
    for (int mf = 0; mf < 4; ++mf) {
      const int r = wm * 128 + (mf + 4) * 16 + lr;
      #pragma unroll
      for (int ks = 0; ks < 2; ++ks)
        a[mf][ks] = *(const bf16x8*)(Ac + r * 64 + (((ks * 4 + kc) ^ (r & 7)) << 3));
    }
    if (more) {
      stageB(nxt, 1, kk);
      asm volatile("s_waitcnt vmcnt(4)" ::: "memory");
    }
    asm volatile("s_barrier" ::: "memory");
    QUAD(4, 0)
    asm volatile("s_barrier" ::: "memory");

    // ---- phase 4: stage u3(t+1); q(4..7, 2..3) ----
    if (more) {
      stageA(nxt, 1, kk);
      asm volatile("s_waitcnt vmcnt(4)" ::: "memory");
    }
    asm volatile("s_barrier" ::: "memory");
    QUAD(4, 2)
    asm volatile("s_barrier" ::: "memory");
  }
  #undef QUAD

  // ---- epilogue: silu(even)*odd -> hid bf16; mask rows beyond segment ----
  const int fcol0 = (n0 >> 1) + wn * 32;
  #pragma unroll
  for (int mf = 0; mf < 8; ++mf) {
    const int row = m0 + wm * 128 + mf * 16 + (kc << 2);
    #pragma unroll
    for (int nf = 0; nf < 4; ++nf) {
      #pragma unroll
      for (int rr = 0; rr < 4; ++rr) {
        const float v = acc[mf][nf][rr];
        const float o = __shfl_xor(v, 1, 64);
        const float h = (l & 1) ? o : v;
        const float g = (l & 1) ? v : o;
        const float res = (h / (1.f + __expf(-h))) * g;
        const float vc = __shfl(res, (l & 48) | ((l & 7) << 1), 64);
        if (lr < 8 && row + rr < mend)
          hid[(size_t)(row + rr) * FDIM + fcol0 + nf * 8 + (l & 7)] = f2b(vc);
      }
    }
  }
}

// ---------------- GEMM2: 128x128 tile, 2-barrier (unchanged, proven) ----------------
__global__ void moe_gemm2(const unsigned short* __restrict__ A,
                          const unsigned short* __restrict__ B,
                          const int* __restrict__ base,
                          const int* __restrict__ rtok, const float* __restrict__ rgw,
                          float* __restrict__ out) {
  constexpr int KDIM = FDIM;      // 4096
  constexpr int NDIM = DDIM;      // 2048

  const int nwg = gridDim.x;
  const int q8 = nwg >> 3;
  const int bid = blockIdx.x;
  const int swz = (bid & 7) * q8 + (bid >> 3);
  const int mt = swz % MAXMT;
  const int ntl = swz / MAXMT;

  const int m0 = mt * 128;
  if (m0 >= base[8]) return;
  int e = 0;
  #pragma unroll
  for (int qq = 1; qq < 8; ++qq) if (m0 >= base[qq]) e = qq;
  const int n0 = ntl * 128;
  const unsigned short* Bp = B + (size_t)e * NDIM * KDIM;

  __shared__ __align__(16) unsigned short As[128 * 64];
  __shared__ __align__(16) unsigned short Bs[128 * 64];

  const int tid = threadIdx.x;
  const int l = tid & 63;
  const int w = tid >> 6;
  const int wm = w >> 1, wn = w & 1;
  const int lr = l & 15, kc = l >> 4;

  const f32x4 vzero = {0.f, 0.f, 0.f, 0.f};
  f32x4 acc[4][4];
  #pragma unroll
  for (int i = 0; i < 4; ++i)
    #pragma unroll
    for (int j = 0; j < 4; ++j) acc[i][j] = vzero;

  const int srow = w * 32 + (l >> 3);
  const int sc = l & 7;
  const unsigned short* Arow = A + (size_t)(m0 + srow) * KDIM;
  const unsigned short* Brow = Bp + (size_t)(n0 + srow) * KDIM;

  for (int k0 = 0; k0 < KDIM; k0 += 64) {
    #pragma unroll
    for (int qq = 0; qq < 4; ++qq) {
      const int r = srow + qq * 8;
      const int cg = (sc ^ (r & 7)) << 3;
      gload_lds16(Arow + (size_t)qq * 8 * KDIM + k0 + cg,
                  (unsigned short*)As + w * 2048 + qq * 512);
      gload_lds16(Brow + (size_t)qq * 8 * KDIM + k0 + cg,
                  (unsigned short*)Bs + w * 2048 + qq * 512);
    }
    __syncthreads();
    #pragma unroll
    for (int ks = 0; ks < 2; ++ks) {
      bf16x8 af[4], bfr[4];
      #pragma unroll
      for (int mf = 0; mf < 4; ++mf) {
        const int r = wm * 64 + mf * 16 + lr;
        const int c = (ks * 4 + kc) ^ (r & 7);
        af[mf] = *(const bf16x8*)((const char*)As + r * 128 + c * 16);
      }
      #pragma unroll
      for (int nf = 0; nf < 4; ++nf) {
        const int n = wn * 64 + nf * 16 + lr;
        const int c = (ks * 4 + kc) ^ (n & 7);
        bfr[nf] = *(const bf16x8*)((const char*)Bs + n * 128 + c * 16);
      }
      #pragma unroll
      for (int mf = 0; mf < 4; ++mf)
        #pragma unroll
        for (int nf = 0; nf < 4; ++nf)
          acc[mf][nf] = __builtin_amdgcn_mfma_f32_16x16x32_bf16(af[mf], bfr[nf], acc[mf][nf], 0, 0, 0);
    }
    __syncthreads();
  }
  #pragma unroll
  for (int mf = 0; mf < 4; ++mf) {
    const int row = m0 + wm * 64 + mf * 16 + (kc << 2);
    #pragma unroll
    for (int rr = 0; rr < 4; ++rr) {
      const int tok = rtok[row + rr];
      if (tok < 0) continue;
      const float gwt = rgw[row + rr];
      float* orow = out + (size_t)tok * DDIM;
      #pragma unroll
      for (int nf = 0; nf < 4; ++nf) {
        const int col = n0 + wn * 64 + nf * 16 + lr;
        atomicAdd(orow + col, gwt * acc[mf][nf][rr]);
      }
    }
  }
}

// ---------------- launch ----------------
// ws layout (bytes)
#define OFF_CNT   0u
#define OFF_BASE  64u
#define OFF_TE    128u          // 40 ints
#define OFF_TM0   512u
#define OFF_TEND  896u
#define OFF_SELE  4096u
#define OFF_SELW  36864u
#define OFF_RTOK  69632u
#define OFF_RGW   106496u
#define OFF_XC    1048576u      // 9216*2048 bf16 = 37748736
#define OFF_HID   38797312u     // 9216*4096 bf16 = 75497472
#define OFF_WBUF  114294784u    // 8*8192*2048 bf16 = 268435456 -> end ~365 MB

extern "C" void kernel_launch(void* const* d_in, const int* in_sizes, int n_in,
                              void* d_out, int out_size, void* d_ws, size_t ws_size,
                              hipStream_t stream) {
  const float* x  = (const float*)d_in[0];
  const float* gw = (const float*)d_in[1];
  const float* w1 = (const float*)d_in[2];
  const float* w3 = (const float*)d_in[3];
  const float* w2 = (const float*)d_in[4];
  float* out = (float*)d_out;
  char* ws = (char*)d_ws;

  int*   cnt   = (int*)(ws + OFF_CNT);
  int*   base  = (int*)(ws + OFF_BASE);
  int*   tE    = (int*)(ws + OFF_TE);
  int*   tM0   = (int*)(ws + OFF_TM0);
  int*   tEnd  = (int*)(ws + OFF_TEND);
  int*   sel_e = (int*)(ws + OFF_SELE);
  float* sel_w = (float*)(ws + OFF_SELW);
  int*   rtok  = (int*)(ws + OFF_RTOK);
  float* rgw   = (float*)(ws + OFF_RGW);
  unsigned short* xc   = (unsigned short*)(ws + OFF_XC);
  unsigned short* hid  = (unsigned short*)(ws + OFF_HID);
  unsigned short* wbuf = (unsigned short*)(ws + OFF_WBUF);

  hipMemsetAsync(d_out, 0, (size_t)T_TOK * DDIM * sizeof(float), stream);
  gate_topk<<<T_TOK / 4, 256, 0, stream>>>(x, gw, sel_e, sel_w);
  build_lists<<<1, 256, 0, stream>>>(sel_e, sel_w, cnt, base, rtok, rgw, tE, tM0, tEnd);
  gather_x<<<MAXROWS, 256, 0, stream>>>(x, base, rtok, xc);
  // w13t[e][8192][2048]: even rows = w1 cols, odd rows = w3 cols
  conv_t<<<dim3(32, 64, 8), 256, 0, stream>>>(w1, wbuf, DDIM, FDIM, 2, 0);
  conv_t<<<dim3(32, 64, 8), 256, 0, stream>>>(w3, wbuf, DDIM, FDIM, 2, 1);
  // gemm1: 40 m-tiles x 32 n-tiles = 1280 blocks (%8==0)
  moe_gemm1<<<NT256 * 32, 512, 0, stream>>>(xc, wbuf, tE, tM0, tEnd, hid);
  // reuse wbuf for w2t[e][2048][4096]
  conv_t<<<dim3(64, 32, 8), 256, 0, stream>>>(w2, wbuf, FDIM, DDIM, 1, 0);
  moe_gemm2<<<MAXMT * 16, 256, 0, stream>>>(hid, wbuf, base, rtok, rgw, out);
}